// Round 1
// baseline (845.551 us; speedup 1.0000x reference)
//
#include <hip/hip_runtime.h>

static constexpr unsigned TSIZE = 1u << 19;
static constexpr unsigned TMASK = TSIZE - 1u;

__global__ __launch_bounds__(256, 4)
void resnet_fused(const float* __restrict__ xyz,
                  const float* __restrict__ tables,
                  const float* __restrict__ Win,
                  const float* __restrict__ Wh,
                  const float* __restrict__ Wout,
                  float* __restrict__ out, int N)
{
    // Stage xyz through LDS: 768 consecutive floats, coalesced global read,
    // then stride-3 LDS read (stride 3 is coprime to 32 banks -> conflict-free).
    __shared__ float sxyz[768];
    const int bbase = blockIdx.x * 256;
    {
        const int g3 = bbase * 3;
        #pragma unroll
        for (int t = 0; t < 3; ++t) {
            int sidx = (int)threadIdx.x + t * 256;
            int g = g3 + sidx;
            sxyz[sidx] = (g < 3 * N) ? xyz[g] : 0.0f;
        }
    }
    __syncthreads();
    const int i = bbase + (int)threadIdx.x;

    const float px = (sxyz[threadIdx.x * 3 + 0] + 5.0f) * 0.1f;
    const float py = (sxyz[threadIdx.x * 3 + 1] + 5.0f) * 0.1f;
    const float pz = (sxyz[threadIdx.x * 3 + 2] + 5.0f) * 0.1f;

    // ---- hash-grid encoding: 4 levels, 8 corners, float2 features ----
    float enc[8];
    #pragma unroll
    for (int l = 0; l < 4; ++l) {
        const float res = 200.0f * (float)(1 << l);
        const float fx = px * res, fy = py * res, fz = pz * res;
        const float flx = floorf(fx), fly = floorf(fy), flz = floorf(fz);
        const float frx = fx - flx, fry = fy - fly, frz = fz - flz;
        const unsigned bx = (unsigned)flx, by = (unsigned)fly, bz = (unsigned)flz;
        const unsigned hy0 = by * 2654435761u, hy1 = (by + 1u) * 2654435761u;
        const unsigned hz0 = bz * 805459861u,  hz1 = (bz + 1u) * 805459861u;
        const float wx[2] = {1.0f - frx, frx};
        const float wy[2] = {1.0f - fry, fry};
        const float wz[2] = {1.0f - frz, frz};
        const float2* tab = (const float2*)(tables + (size_t)l * TSIZE * 2u);
        float e0 = 0.0f, e1 = 0.0f;
        #pragma unroll
        for (int c = 0; c < 8; ++c) {
            unsigned h = (bx + (unsigned)(c & 1))
                       ^ ((c & 2) ? hy1 : hy0)
                       ^ ((c & 4) ? hz1 : hz0);
            float2 f = tab[h & TMASK];                       // random 8B gather (L2/L3)
            float w = wx[c & 1] * wy[(c >> 1) & 1] * wz[(c >> 2) & 1];
            e0 = fmaf(f.x, w, e0);
            e1 = fmaf(f.y, w, e1);
        }
        enc[2 * l]     = e0;
        enc[2 * l + 1] = e1;
    }

    // ---- layer 1: h1 = leaky_relu(enc @ Win), Win is [8][64] row-major ----
    // k-outer / j-inner so weight reads are contiguous rows -> s_load_dwordx16.
    float h1[64];
    #pragma unroll
    for (int j = 0; j < 64; ++j) h1[j] = 0.0f;
    #pragma unroll
    for (int k = 0; k < 8; ++k) {
        const float e = enc[k];
        #pragma unroll
        for (int j = 0; j < 64; ++j)
            h1[j] = fmaf(e, Win[k * 64 + j], h1[j]);
    }
    #pragma unroll
    for (int j = 0; j < 64; ++j)
        h1[j] = (h1[j] >= 0.0f) ? h1[j] : 0.01f * h1[j];

    // ---- layers 2+3 fused: sdf = sum_j leaky(sum_k h1[k]*Wh[k][j]) * Wout[j] ----
    // j blocked by 16: per k a contiguous 16-float chunk of Wh row k (dwordx16),
    // only 16 live accumulators on top of h1[64].
    float sdf = 0.0f;
    for (int j0 = 0; j0 < 64; j0 += 16) {
        float acc[16];
        #pragma unroll
        for (int jj = 0; jj < 16; ++jj) acc[jj] = 0.0f;
        #pragma unroll 8
        for (int k = 0; k < 64; ++k) {
            const float hk = h1[k];
            #pragma unroll
            for (int jj = 0; jj < 16; ++jj)
                acc[jj] = fmaf(hk, Wh[k * 64 + j0 + jj], acc[jj]);
        }
        #pragma unroll
        for (int jj = 0; jj < 16; ++jj) {
            float a = acc[jj];
            a = (a >= 0.0f) ? a : 0.01f * a;
            sdf = fmaf(a, Wout[j0 + jj], sdf);
        }
    }

    if (i < N) out[i] = sdf * 0.1f;
}

extern "C" void kernel_launch(void* const* d_in, const int* in_sizes, int n_in,
                              void* d_out, int out_size, void* d_ws, size_t ws_size,
                              hipStream_t stream) {
    const float* xyz    = (const float*)d_in[0];
    const float* tables = (const float*)d_in[1];
    const float* Win    = (const float*)d_in[2];
    const float* Wh     = (const float*)d_in[3];
    const float* Wout   = (const float*)d_in[4];
    float* out = (float*)d_out;

    const int N = in_sizes[0] / 3;           // xyz is [N,3]
    const int blocks = (N + 255) / 256;
    hipLaunchKernelGGL(resnet_fused, dim3(blocks), dim3(256), 0, stream,
                       xyz, tables, Win, Wh, Wout, out, N);
}

// Round 2
// 742.038 us; speedup vs baseline: 1.1395x; 1.1395x over previous
//
#include <hip/hip_runtime.h>
#include <hip/hip_fp16.h>

static constexpr unsigned TSIZE = 1u << 19;
static constexpr unsigned TMASK = TSIZE - 1u;

// ---- prologue: fp32 tables -> fp16 in workspace (d_ws re-poisoned every call) ----
__global__ __launch_bounds__(256)
void cvt_tables(const float4* __restrict__ in, __half2* __restrict__ out, int n4)
{
    int i = blockIdx.x * 256 + threadIdx.x;
    if (i < n4) {
        float4 v = in[i];
        out[2 * i]     = __floats2half2_rn(v.x, v.y);
        out[2 * i + 1] = __floats2half2_rn(v.z, v.w);
    }
}

template <typename TabT>
__global__ __launch_bounds__(256, 8)
void resnet_fused(const float* __restrict__ xyz,
                  const TabT* __restrict__ tables,   // __half2* (fp16 path) or float2*
                  const float* __restrict__ Win,
                  const float* __restrict__ Wh,
                  const float* __restrict__ Wout,
                  float* __restrict__ out, int N)
{
    __shared__ float sxyz[768];
    const int bbase = blockIdx.x * 256;
    {
        const int g3 = bbase * 3;
        #pragma unroll
        for (int t = 0; t < 3; ++t) {
            int sidx = (int)threadIdx.x + t * 256;
            int g = g3 + sidx;
            sxyz[sidx] = (g < 3 * N) ? xyz[g] : 0.0f;
        }
    }
    __syncthreads();
    const int i = bbase + (int)threadIdx.x;

    const float px = (sxyz[threadIdx.x * 3 + 0] + 5.0f) * 0.1f;
    const float py = (sxyz[threadIdx.x * 3 + 1] + 5.0f) * 0.1f;
    const float pz = (sxyz[threadIdx.x * 3 + 2] + 5.0f) * 0.1f;

    // ---- hash-grid encoding: 4 levels x 8 corners, fully unrolled so the
    // compiler can hoist all 32 gathers and cover latency with vmcnt slack ----
    float enc[8];
    #pragma unroll
    for (int l = 0; l < 4; ++l) {
        const float res = 200.0f * (float)(1 << l);
        const float fx = px * res, fy = py * res, fz = pz * res;
        const float flx = floorf(fx), fly = floorf(fy), flz = floorf(fz);
        const float frx = fx - flx, fry = fy - fly, frz = fz - flz;
        const unsigned bx = (unsigned)flx, by = (unsigned)fly, bz = (unsigned)flz;
        const unsigned hy0 = by * 2654435761u, hy1 = (by + 1u) * 2654435761u;
        const unsigned hz0 = bz * 805459861u,  hz1 = (bz + 1u) * 805459861u;
        const float wx[2] = {1.0f - frx, frx};
        const float wy[2] = {1.0f - fry, fry};
        const float wz[2] = {1.0f - frz, frz};
        const TabT* tab = tables + (size_t)l * TSIZE;
        float e0 = 0.0f, e1 = 0.0f;
        #pragma unroll
        for (int c = 0; c < 8; ++c) {
            unsigned h = (bx + (unsigned)(c & 1))
                       ^ ((c & 2) ? hy1 : hy0)
                       ^ ((c & 4) ? hz1 : hz0);
            TabT fv = tab[h & TMASK];                      // random gather (L2/L3)
            float2 f;
            if constexpr (sizeof(TabT) == 4) { f = __half22float2(fv); }
            else                             { f = *(const float2*)&fv; }
            float w = wx[c & 1] * wy[(c >> 1) & 1] * wz[(c >> 2) & 1];
            e0 = fmaf(f.x, w, e0);
            e1 = fmaf(f.y, w, e1);
        }
        enc[2 * l]     = e0;
        enc[2 * l + 1] = e1;
    }

    // ---- layer 1: h1 = leaky_relu(enc @ Win)  (Win rows contiguous -> s_load_dwordx16) ----
    float h1[64];
    #pragma unroll
    for (int j = 0; j < 64; ++j) h1[j] = 0.0f;
    #pragma unroll
    for (int k = 0; k < 8; ++k) {
        const float e = enc[k];
        #pragma unroll
        for (int j = 0; j < 64; ++j)
            h1[j] = fmaf(e, Win[k * 64 + j], h1[j]);
    }
    #pragma unroll
    for (int j = 0; j < 64; ++j)
        h1[j] = (h1[j] >= 0.0f) ? h1[j] : 0.01f * h1[j];

    // ---- layers 2+3 fused, j blocked by 16 ----
    float sdf = 0.0f;
    for (int j0 = 0; j0 < 64; j0 += 16) {
        float acc[16];
        #pragma unroll
        for (int jj = 0; jj < 16; ++jj) acc[jj] = 0.0f;
        #pragma unroll 8
        for (int k = 0; k < 64; ++k) {
            const float hk = h1[k];
            #pragma unroll
            for (int jj = 0; jj < 16; ++jj)
                acc[jj] = fmaf(hk, Wh[k * 64 + j0 + jj], acc[jj]);
        }
        #pragma unroll
        for (int jj = 0; jj < 16; ++jj) {
            float a = acc[jj];
            a = (a >= 0.0f) ? a : 0.01f * a;
            sdf = fmaf(a, Wout[j0 + jj], sdf);
        }
    }

    if (i < N) out[i] = sdf * 0.1f;
}

extern "C" void kernel_launch(void* const* d_in, const int* in_sizes, int n_in,
                              void* d_out, int out_size, void* d_ws, size_t ws_size,
                              hipStream_t stream) {
    const float* xyz    = (const float*)d_in[0];
    const float* tables = (const float*)d_in[1];
    const float* Win    = (const float*)d_in[2];
    const float* Wh     = (const float*)d_in[3];
    const float* Wout   = (const float*)d_in[4];
    float* out = (float*)d_out;

    const int N = in_sizes[0] / 3;           // xyz is [N,3]
    const int blocks = (N + 255) / 256;

    const int tab_floats = in_sizes[1];      // 4 * 2^19 * 2 = 4,194,304
    const size_t fp16_bytes = (size_t)tab_floats * 2;

    if (ws_size >= fp16_bytes) {
        // fp32 -> fp16 table conversion (runs every launch; ~5 us)
        __half2* tab16 = (__half2*)d_ws;
        int n4 = tab_floats / 4;
        hipLaunchKernelGGL(cvt_tables, dim3((n4 + 255) / 256), dim3(256), 0, stream,
                           (const float4*)tables, tab16, n4);
        hipLaunchKernelGGL((resnet_fused<__half2>), dim3(blocks), dim3(256), 0, stream,
                           xyz, tab16, Win, Wh, Wout, out, N);
    } else {
        hipLaunchKernelGGL((resnet_fused<float2>), dim3(blocks), dim3(256), 0, stream,
                           xyz, (const float2*)tables, Win, Wh, Wout, out, N);
    }
}